// Round 7
// baseline (213.173 us; speedup 1.0000x reference)
//
#include <hip/hip_runtime.h>
#include <cmath>

typedef __attribute__((ext_vector_type(8))) short s16x8;   // 8 bf16 = 4 VGPRs (MFMA A/B frag)
typedef __attribute__((ext_vector_type(4))) short s16x4;
typedef __attribute__((ext_vector_type(4))) float f32x4;   // MFMA C/D frag

__device__ __forceinline__ short f2bf(float f) {
    union { float f; unsigned u; } v; v.f = f;
    unsigned r = v.u + 0x7FFFu + ((v.u >> 16) & 1u);   // RNE
    return (short)(r >> 16);
}
__device__ __forceinline__ float bf2f(short s) {
    union { unsigned u; float f; } v; v.u = ((unsigned)(unsigned short)s) << 16;
    return v.f;
}

// ---- ws layout (offsets kept from round 5/6; qc/scores regions now unused) ----
#define EMB_ELEMS 6400064
#define W1SEQ_SH  6400064
#define W1TOP_SH  6404160
#define W2_SH     6408256
#define MW1T_SH   6410304
#define MW2T_SH   6430784
#define CB_SH     10764352

// ============================ K1: prep ============================
__global__ __launch_bounds__(256)
void din_prep_kernel(const float* __restrict__ emb,
                     const float* __restrict__ aw1,
                     const float* __restrict__ aw2,
                     const float* __restrict__ mw1,
                     const float* __restrict__ mw2,
                     short* __restrict__ ws)
{
    const int bid = blockIdx.x;
    const int t = threadIdx.x;
    if (bid < 6251) {
        long e4 = ((long)bid * 256 + t) * 4;
        if (e4 < EMB_ELEMS) {
            float4 v = *(const float4*)(emb + e4);
            s16x4 bv = { f2bf(v.x), f2bf(v.y), f2bf(v.z), f2bf(v.w) };
            *(s16x4*)(ws + e4) = bv;
        }
        return;
    }
    const int wb = bid - 6251;   // 0..7
    if (wb == 0) {               // w1seq frag-linear: frag = nt*2+ks (nt<4,ks<2)
        for (int idx = t; idx < 4096; idx += 256) {
            int j = idx & 7, lane = (idx >> 3) & 63, fr = idx >> 9;
            int n = (fr >> 1) * 16 + (lane & 15);
            int k = (fr & 1) * 32 + (lane >> 4) * 8 + j;
            ws[W1SEQ_SH + idx] = f2bf(aw1[(64 + k) * 64 + n]);
        }
    } else if (wb == 1) {        // w1top frag-linear
        for (int idx = t; idx < 4096; idx += 256) {
            int j = idx & 7, lane = (idx >> 3) & 63, fr = idx >> 9;
            int n = (fr >> 1) * 16 + (lane & 15);
            int k = (fr & 1) * 32 + (lane >> 4) * 8 + j;
            ws[W1TOP_SH + idx] = f2bf(aw1[k * 64 + n]);
        }
    } else if (wb == 2) {        // w2 frag-linear: frag = nt*2+ks (nt<2,ks<2)
        for (int idx = t; idx < 2048; idx += 256) {
            int j = idx & 7, lane = (idx >> 3) & 63, fr = idx >> 9;
            int n = (fr >> 1) * 16 + (lane & 15);
            int k = (fr & 1) * 32 + (lane >> 4) * 8 + j;
            ws[W2_SH + idx] = f2bf(aw2[k * 32 + n]);
        }
    } else if (wb == 3) {        // mw2 frag-linear: frag = nt*4+ks (nt<4,ks<4)
        for (int idx = t; idx < 8192; idx += 256) {
            int j = idx & 7, lane = (idx >> 3) & 63, fr = idx >> 9;
            int n = (fr >> 2) * 16 + (lane & 15);
            int k = (fr & 3) * 32 + (lane >> 4) * 8 + j;
            ws[MW2T_SH + idx] = f2bf(mw2[k * 64 + n]);
        }
    } else {                     // wb 4..7: mw1 frag-linear quarter: frag = nt*5+ks (nt<8,ks<5)
        const int base = (wb - 4) * 5120;
        for (int ii = t; ii < 5120; ii += 256) {
            int idx = base + ii;
            int j = idx & 7, lane = (idx >> 3) & 63, fr = idx >> 9;
            int nt = fr / 5, ks = fr - nt * 5;
            int n = nt * 16 + (lane & 15);
            int k = ks * 32 + (lane >> 4) * 8 + j;
            ws[MW1T_SH + idx] = f2bf(mw1[k * 128 + n]);
        }
    }
}

// ============ K2: fused per-b attention: qc + scores + softmax + pool + ctx ============
#define H1_PITCH 72
__global__ __launch_bounds__(256)
void din_att_fused(const int* __restrict__ item_seq,
                   const int* __restrict__ seq_len_p,
                   const int* __restrict__ tgt_item,
                   const float* __restrict__ ctx_feat,
                   const float* __restrict__ ab1,
                   const float* __restrict__ ab2,
                   const float* __restrict__ aw3, const float* __restrict__ ab3,
                   const float* __restrict__ cw,  const float* __restrict__ cb,
                   short* __restrict__ ws)
{
    const int t = threadIdx.x, lane = t & 63, wave = t >> 6;
    const int quad = lane >> 4, r16 = lane & 15;
    __shared__ short s_w1[4096];              // 8 KB frag-linear w1seq
    __shared__ short s_h1[4][16 * H1_PITCH];  // 9 KB
    __shared__ float s_sc[208];               // scores -> exp weights
    __shared__ float s_qc[64];
    __shared__ float s_pool[4][64];
    __shared__ float s_ctx[32];
    __shared__ float s_inv;

    const int b   = blockIdx.x;
    const int len = seq_len_p[b];
    const int tgt = tgt_item[b];
    const short* embbf = ws;

    // ---- stage w1seq frags (linear, conflict-free) ----
    {
        const s16x8* src = (const s16x8*)(ws + W1SEQ_SH);
        s16x8* dst = (s16x8*)s_w1;
        dst[t]       = src[t];
        dst[t + 256] = src[t + 256];
    }

    // ---- per-wave gathers: issue all up front, RETAIN for pooling ----
    const int row0 = wave * 64;
    const int nc = (row0 < len) ? min(4, (len - row0 + 15) >> 4) : 0;
    s16x8 af[4][2];
    #pragma unroll
    for (int ck = 0; ck < 4; ++ck) {
        if (ck < nc) {
            int r = row0 + ck * 16 + r16; if (r > 199) r = 199;
            const int it = item_seq[b * 200 + r];
            af[ck][0] = *(const s16x8*)(embbf + it * 64 + quad * 8);
            af[ck][1] = *(const s16x8*)(embbf + it * 64 + 32 + quad * 8);
        }
    }
    s16x8 w2r[4];
    #pragma unroll
    for (int fr = 0; fr < 4; ++fr)
        w2r[fr] = *(const s16x8*)(ws + W2_SH + (fr * 64 + lane) * 8);
    const float bias2_lo = ab2[r16], bias2_hi = ab2[16 + r16];
    const float w3_lo    = aw3[r16], w3_hi    = aw3[16 + r16];
    const float b3       = ab3[0];

    // ---- wave 0: qc = tgt_emb @ w1top + ab1 (single live A-row MFMA) ----
    if (wave == 0) {
        s16x8 a0 = {}, a1 = {};
        if (r16 == 0) {
            a0 = *(const s16x8*)(embbf + tgt * 64 + quad * 8);
            a1 = *(const s16x8*)(embbf + tgt * 64 + 32 + quad * 8);
        }
        f32x4 qacc[4] = {{0,0,0,0},{0,0,0,0},{0,0,0,0},{0,0,0,0}};
        #pragma unroll
        for (int nt = 0; nt < 4; ++nt) {
            s16x8 b_0 = *(const s16x8*)(ws + W1TOP_SH + ((nt * 2 + 0) * 64 + lane) * 8);
            s16x8 b_1 = *(const s16x8*)(ws + W1TOP_SH + ((nt * 2 + 1) * 64 + lane) * 8);
            qacc[nt] = __builtin_amdgcn_mfma_f32_16x16x32_bf16(a0, b_0, qacc[nt], 0, 0, 0);
            qacc[nt] = __builtin_amdgcn_mfma_f32_16x16x32_bf16(a1, b_1, qacc[nt], 0, 0, 0);
        }
        if (quad == 0) {
            #pragma unroll
            for (int nt = 0; nt < 4; ++nt)      // D row0 = (quad==0, reg 0)
                s_qc[nt * 16 + r16] = qacc[nt][0] + ab1[nt * 16 + r16];
        }
    }
    __syncthreads();   // w1 staged + qc ready

    float qcv[4];
    #pragma unroll
    for (int nt = 0; nt < 4; ++nt) qcv[nt] = s_qc[nt * 16 + r16];
    short* h1w = s_h1[wave];

    // ---- attention MLP per chunk; scores -> LDS ----
    #pragma unroll
    for (int ck = 0; ck < 4; ++ck) {
        if (ck >= nc) break;
        f32x4 acc[4] = {{0,0,0,0},{0,0,0,0},{0,0,0,0},{0,0,0,0}};
        #pragma unroll
        for (int nt = 0; nt < 4; ++nt) {
            s16x8 b_0 = *(const s16x8*)&s_w1[((nt * 2 + 0) * 64 + lane) * 8];
            s16x8 b_1 = *(const s16x8*)&s_w1[((nt * 2 + 1) * 64 + lane) * 8];
            acc[nt] = __builtin_amdgcn_mfma_f32_16x16x32_bf16(af[ck][0], b_0, acc[nt], 0, 0, 0);
            acc[nt] = __builtin_amdgcn_mfma_f32_16x16x32_bf16(af[ck][1], b_1, acc[nt], 0, 0, 0);
        }
        #pragma unroll
        for (int nt = 0; nt < 4; ++nt)
            #pragma unroll
            for (int rr = 0; rr < 4; ++rr) {          // D: row=quad*4+rr, col=nt*16+r16
                float v = fmaxf(acc[nt][rr] + qcv[nt], 0.f);
                h1w[(quad * 4 + rr) * H1_PITCH + nt * 16 + r16] = f2bf(v);
            }
        __builtin_amdgcn_wave_barrier();              // wave-local LDS RAW

        s16x8 h0  = *(const s16x8*)&h1w[r16 * H1_PITCH + quad * 8];
        s16x8 h1v = *(const s16x8*)&h1w[r16 * H1_PITCH + 32 + quad * 8];
        f32x4 c2[2] = {{0,0,0,0},{0,0,0,0}};
        #pragma unroll
        for (int nt = 0; nt < 2; ++nt) {
            c2[nt] = __builtin_amdgcn_mfma_f32_16x16x32_bf16(h0,  w2r[nt * 2],     c2[nt], 0, 0, 0);
            c2[nt] = __builtin_amdgcn_mfma_f32_16x16x32_bf16(h1v, w2r[nt * 2 + 1], c2[nt], 0, 0, 0);
        }
        #pragma unroll
        for (int rr = 0; rr < 4; ++rr) {
            float p = fmaxf(c2[0][rr] + bias2_lo, 0.f) * w3_lo
                    + fmaxf(c2[1][rr] + bias2_hi, 0.f) * w3_hi;
            p += __shfl_xor(p, 8);
            p += __shfl_xor(p, 4);
            p += __shfl_xor(p, 2);
            p += __shfl_xor(p, 1);
            int orow = row0 + ck * 16 + quad * 4 + rr;
            if (r16 == 0 && orow < 200) s_sc[orow] = p + b3;
        }
        __builtin_amdgcn_wave_barrier();
    }
    __syncthreads();   // all scores in LDS

    // ---- wave 0: softmax (exp weights left unnormalized in s_sc); wave1: ctx; wave2: tgt copy ----
    short* comb = ws + CB_SH + b * 160;
    if (wave == 0) {
        float m = -1e30f;
        for (int l = lane; l < len; l += 64) m = fmaxf(m, s_sc[l]);
        #pragma unroll
        for (int off = 32; off; off >>= 1) m = fmaxf(m, __shfl_xor(m, off));
        float e = 0.f;
        for (int l = lane; l < len; l += 64) {
            float v = __expf(s_sc[l] - m);
            s_sc[l] = v;
            e += v;
        }
        #pragma unroll
        for (int off = 32; off; off >>= 1) e += __shfl_xor(e, off);
        if (lane == 0) s_inv = 1.f / e;
    } else if (wave == 1) {
        if (lane < 32) {
            float a = cb[lane];
            #pragma unroll
            for (int k = 0; k < 9; ++k) a += ctx_feat[b * 9 + k] * cw[k * 32 + lane];
            s_ctx[lane] = fmaxf(a, 0.f);
        }
    } else if (wave == 2) {
        comb[64 + lane] = embbf[tgt * 64 + lane];
    }
    __syncthreads();   // exp weights ready

    // ---- pooling from RETAINED registers: p[d] += w_row * emb_row[d] ----
    float p[16];
    #pragma unroll
    for (int i = 0; i < 16; ++i) p[i] = 0.f;
    #pragma unroll
    for (int ck = 0; ck < 4; ++ck) {
        if (ck >= nc) break;
        const int row = row0 + ck * 16 + r16;
        const float w = (row < len) ? s_sc[row] : 0.f;
        #pragma unroll
        for (int j = 0; j < 8; ++j) {
            p[j]     += w * bf2f(af[ck][0][j]);
            p[8 + j] += w * bf2f(af[ck][1][j]);
        }
    }
    #pragma unroll
    for (int i = 0; i < 16; ++i) {
        p[i] += __shfl_xor(p[i], 1);
        p[i] += __shfl_xor(p[i], 2);
        p[i] += __shfl_xor(p[i], 4);
        p[i] += __shfl_xor(p[i], 8);
    }
    if (r16 == 0) {
        #pragma unroll
        for (int j = 0; j < 8; ++j) {
            s_pool[wave][quad * 8 + j]      = p[j];
            s_pool[wave][32 + quad * 8 + j] = p[8 + j];
        }
    }
    __syncthreads();

    if (t < 64) {
        float a = (s_pool[0][t] + s_pool[1][t] + s_pool[2][t] + s_pool[3][t]) * s_inv;
        comb[t] = f2bf(a);
    } else if (t < 96) {
        comb[128 + (t - 64)] = f2bf(s_ctx[t - 64]);
    }
}

// ============================ K3: batched final MLP via MFMA (16 b's/wave, 1 wave/block) =====
__global__ __launch_bounds__(64)
void din_mlp_kernel(const float* __restrict__ mb1,
                    const float* __restrict__ mb2,
                    const float* __restrict__ mw3, const float* __restrict__ mb3,
                    const short* __restrict__ ws,
                    float* __restrict__ out)
{
    const int lane = threadIdx.x & 63;
    const int quad = lane >> 4, r16 = lane & 15;
    __shared__ short s_h1[16 * 136];
    __shared__ short s_h2[16 * 72];

    const int b0 = blockIdx.x * 16;
    const short* comb = ws + CB_SH;
    const short* w1   = ws + MW1T_SH;
    const short* w2   = ws + MW2T_SH;

    // layer1: (16x160) @ (160x128), K=160 in 5 steps
    s16x8 a[5];
    #pragma unroll
    for (int ks = 0; ks < 5; ++ks)
        a[ks] = *(const s16x8*)(comb + (b0 + r16) * 160 + ks * 32 + quad * 8);
    f32x4 acc[8] = {{0,0,0,0},{0,0,0,0},{0,0,0,0},{0,0,0,0},{0,0,0,0},{0,0,0,0},{0,0,0,0},{0,0,0,0}};
    #pragma unroll
    for (int nt = 0; nt < 8; ++nt)
        #pragma unroll
        for (int ks = 0; ks < 5; ++ks) {
            s16x8 bf = *(const s16x8*)(w1 + ((nt * 5 + ks) * 64 + lane) * 8);
            acc[nt] = __builtin_amdgcn_mfma_f32_16x16x32_bf16(a[ks], bf, acc[nt], 0, 0, 0);
        }
    #pragma unroll
    for (int nt = 0; nt < 8; ++nt) {
        float bias = mb1[nt * 16 + r16];
        #pragma unroll
        for (int rr = 0; rr < 4; ++rr)
            s_h1[(quad * 4 + rr) * 136 + nt * 16 + r16] = f2bf(fmaxf(acc[nt][rr] + bias, 0.f));
    }
    __builtin_amdgcn_wave_barrier();

    // layer2: (16x128) @ (128x64), K=128 in 4 steps
    s16x8 a2[4];
    #pragma unroll
    for (int ks = 0; ks < 4; ++ks)
        a2[ks] = *(const s16x8*)&s_h1[r16 * 136 + ks * 32 + quad * 8];
    f32x4 acc2[4] = {{0,0,0,0},{0,0,0,0},{0,0,0,0},{0,0,0,0}};
    #pragma unroll
    for (int nt = 0; nt < 4; ++nt)
        #pragma unroll
        for (int ks = 0; ks < 4; ++ks) {
            s16x8 bf = *(const s16x8*)(w2 + ((nt * 4 + ks) * 64 + lane) * 8);
            acc2[nt] = __builtin_amdgcn_mfma_f32_16x16x32_bf16(a2[ks], bf, acc2[nt], 0, 0, 0);
        }
    #pragma unroll
    for (int nt = 0; nt < 4; ++nt) {
        float bias = mb2[nt * 16 + r16];
        #pragma unroll
        for (int rr = 0; rr < 4; ++rr)
            s_h2[(quad * 4 + rr) * 72 + nt * 16 + r16] = f2bf(fmaxf(acc2[nt][rr] + bias, 0.f));
    }
    __builtin_amdgcn_wave_barrier();

    // layer3: (16x64) @ (64x1) + sigmoid; lane=(row r16, dim-group quad)
    float p = 0.f;
    #pragma unroll
    for (int j = 0; j < 16; ++j)
        p += bf2f(s_h2[r16 * 72 + quad * 16 + j]) * mw3[quad * 16 + j];
    p += __shfl_xor(p, 16);
    p += __shfl_xor(p, 32);
    if (quad == 0) out[b0 + r16] = 1.f / (1.f + __expf(-(p + mb3[0])));
}

extern "C" void kernel_launch(void* const* d_in, const int* in_sizes, int n_in,
                              void* d_out, int out_size, void* d_ws, size_t ws_size,
                              hipStream_t stream)
{
    const int*   item_seq  = (const int*)  d_in[0];
    // d_in[1] click_sequence: unused by the reference
    const int*   seq_len   = (const int*)  d_in[2];
    const int*   tgt_item  = (const int*)  d_in[3];
    const float* ctx_feat  = (const float*)d_in[4];
    const float* emb       = (const float*)d_in[5];
    const float* aw1 = (const float*)d_in[6];
    const float* ab1 = (const float*)d_in[7];
    const float* aw2 = (const float*)d_in[8];
    const float* ab2 = (const float*)d_in[9];
    const float* aw3 = (const float*)d_in[10];
    const float* ab3 = (const float*)d_in[11];
    const float* cw  = (const float*)d_in[12];
    const float* cb  = (const float*)d_in[13];
    const float* mw1 = (const float*)d_in[14];
    const float* mb1 = (const float*)d_in[15];
    const float* mw2 = (const float*)d_in[16];
    const float* mb2 = (const float*)d_in[17];
    const float* mw3 = (const float*)d_in[18];
    const float* mb3 = (const float*)d_in[19];
    float* out = (float*)d_out;
    short* ws  = (short*)d_ws;

    hipLaunchKernelGGL(din_prep_kernel, dim3(6259), dim3(256), 0, stream,
                       emb, aw1, aw2, mw1, mw2, ws);
    hipLaunchKernelGGL(din_att_fused, dim3(8192), dim3(256), 0, stream,
                       item_seq, seq_len, tgt_item, ctx_feat,
                       ab1, ab2, aw3, ab3, cw, cb, ws);
    hipLaunchKernelGGL(din_mlp_kernel, dim3(512), dim3(64), 0, stream,
                       mb1, mb2, mw3, mb3, ws, out);
}

// Round 8
// 196.934 us; speedup vs baseline: 1.0825x; 1.0825x over previous
//
#include <hip/hip_runtime.h>
#include <cmath>

typedef __attribute__((ext_vector_type(8))) short s16x8;   // 8 bf16 = 4 VGPRs (MFMA A/B frag)
typedef __attribute__((ext_vector_type(4))) short s16x4;
typedef __attribute__((ext_vector_type(4))) float f32x4;   // MFMA C/D frag

__device__ __forceinline__ short f2bf(float f) {
    union { float f; unsigned u; } v; v.f = f;
    unsigned r = v.u + 0x7FFFu + ((v.u >> 16) & 1u);   // RNE
    return (short)(r >> 16);
}
__device__ __forceinline__ float bf2f(short s) {
    union { unsigned u; float f; } v; v.u = ((unsigned)(unsigned short)s) << 16;
    return v.f;
}

// ---- ws layout ----
// shorts: [emb_bf16 6,400,064][w1seqF 4096][w1topF 4096][w2F 2048][mw1F 20480][mw2F 8192]
// shorts (from 10,764,352): [comb_bf16 8192*160]
#define EMB_ELEMS 6400064
#define W1SEQ_SH  6400064
#define W1TOP_SH  6404160
#define W2_SH     6408256
#define MW1T_SH   6410304
#define MW2T_SH   6430784
#define CB_SH     10764352

// ============================ K1: prep ============================
__global__ __launch_bounds__(256)
void din_prep_kernel(const float* __restrict__ emb,
                     const float* __restrict__ aw1,
                     const float* __restrict__ aw2,
                     const float* __restrict__ mw1,
                     const float* __restrict__ mw2,
                     short* __restrict__ ws)
{
    const int bid = blockIdx.x;
    const int t = threadIdx.x;
    if (bid < 6251) {
        long e4 = ((long)bid * 256 + t) * 4;
        if (e4 < EMB_ELEMS) {
            float4 v = *(const float4*)(emb + e4);
            s16x4 bv = { f2bf(v.x), f2bf(v.y), f2bf(v.z), f2bf(v.w) };
            *(s16x4*)(ws + e4) = bv;
        }
        return;
    }
    const int wb = bid - 6251;   // 0..7
    if (wb == 0) {               // w1seq frag-linear: frag = nt*2+ks (nt<4,ks<2)
        for (int idx = t; idx < 4096; idx += 256) {
            int j = idx & 7, lane = (idx >> 3) & 63, fr = idx >> 9;
            int n = (fr >> 1) * 16 + (lane & 15);
            int k = (fr & 1) * 32 + (lane >> 4) * 8 + j;
            ws[W1SEQ_SH + idx] = f2bf(aw1[(64 + k) * 64 + n]);
        }
    } else if (wb == 1) {        // w1top frag-linear
        for (int idx = t; idx < 4096; idx += 256) {
            int j = idx & 7, lane = (idx >> 3) & 63, fr = idx >> 9;
            int n = (fr >> 1) * 16 + (lane & 15);
            int k = (fr & 1) * 32 + (lane >> 4) * 8 + j;
            ws[W1TOP_SH + idx] = f2bf(aw1[k * 64 + n]);
        }
    } else if (wb == 2) {        // w2 frag-linear: frag = nt*2+ks (nt<2,ks<2)
        for (int idx = t; idx < 2048; idx += 256) {
            int j = idx & 7, lane = (idx >> 3) & 63, fr = idx >> 9;
            int n = (fr >> 1) * 16 + (lane & 15);
            int k = (fr & 1) * 32 + (lane >> 4) * 8 + j;
            ws[W2_SH + idx] = f2bf(aw2[k * 32 + n]);
        }
    } else if (wb == 3) {        // mw2 frag-linear: frag = nt*4+ks (nt<4,ks<4)
        for (int idx = t; idx < 8192; idx += 256) {
            int j = idx & 7, lane = (idx >> 3) & 63, fr = idx >> 9;
            int n = (fr >> 2) * 16 + (lane & 15);
            int k = (fr & 3) * 32 + (lane >> 4) * 8 + j;
            ws[MW2T_SH + idx] = f2bf(mw2[k * 64 + n]);
        }
    } else {                     // wb 4..7: mw1 frag-linear quarter: frag = nt*5+ks (nt<8,ks<5)
        const int base = (wb - 4) * 5120;
        for (int ii = t; ii < 5120; ii += 256) {
            int idx = base + ii;
            int j = idx & 7, lane = (idx >> 3) & 63, fr = idx >> 9;
            int nt = fr / 5, ks = fr - nt * 5;
            int n = nt * 16 + (lane & 15);
            int k = ks * 32 + (lane >> 4) * 8 + j;
            ws[MW1T_SH + idx] = f2bf(mw1[k * 128 + n]);
        }
    }
}

// ============ K2: fused attention, wave-independent online softmax ============
// wave w handles chunks {w, w+4, w+8, w+12} (round-robin, balanced).
// Only 2 block barriers: weight staging (entry) and partial combine (exit).
#define H1_PITCH 72
__global__ __launch_bounds__(256)
void din_att_v2(const int* __restrict__ item_seq,
                const int* __restrict__ seq_len_p,
                const int* __restrict__ tgt_item,
                const float* __restrict__ ctx_feat,
                const float* __restrict__ ab1,
                const float* __restrict__ ab2,
                const float* __restrict__ aw3, const float* __restrict__ ab3,
                const float* __restrict__ cw,  const float* __restrict__ cb,
                short* __restrict__ ws)
{
    const int t = threadIdx.x, lane = t & 63, wave = t >> 6;
    const int quad = lane >> 4, r16 = lane & 15;
    __shared__ short s_wall[10240];           // [0,4096) w1seq | [4096,8192) w1top | [8192,10240) w2
    __shared__ short s_h1[4][16 * H1_PITCH];  // per-wave H1 roundtrip
    __shared__ float s_sc[4][64];             // per-wave raw scores (local chunk order)
    __shared__ float s_pool[4][64];           // per-wave unnormalized pooled partial
    __shared__ float s_m[4], s_e[4];

    const int b   = blockIdx.x;
    const int len = seq_len_p[b];
    const int tgt = tgt_item[b];
    const short* embbf = ws;

    // ---- stage all attention weights (contiguous in ws, frag-linear) ----
    {
        const s16x8* src = (const s16x8*)(ws + W1SEQ_SH);
        s16x8* dst = (s16x8*)s_wall;
        #pragma unroll
        for (int i = 0; i < 2; ++i) dst[t + i * 256] = src[t + i * 256];
        if (t < 128) dst[t + 512] = src[t + 512];
    }

    // ---- issue gathers before the barrier (latency overlaps staging) ----
    bool act[4];
    s16x8 af[4][2];
    #pragma unroll
    for (int ci = 0; ci < 4; ++ci) {
        const int c = wave + ci * 4;
        act[ci] = (c < 13) && (c * 16 < len);
        if (act[ci]) {
            int r = c * 16 + r16; if (r > 199) r = 199;
            const int it = item_seq[b * 200 + r];
            af[ci][0] = *(const s16x8*)(embbf + it * 64 + quad * 8);
            af[ci][1] = *(const s16x8*)(embbf + it * 64 + 32 + quad * 8);
        }
    }
    s16x8 at0 = {}, at1 = {};
    if (r16 == 0) {
        at0 = *(const s16x8*)(embbf + tgt * 64 + quad * 8);
        at1 = *(const s16x8*)(embbf + tgt * 64 + 32 + quad * 8);
    }
    __syncthreads();   // weights staged (gathers also drained here)

    // ---- qc redundant per wave: tgt row through w1top, broadcast from D row 0 ----
    float qcv[4];
    {
        f32x4 qacc[4] = {{0,0,0,0},{0,0,0,0},{0,0,0,0},{0,0,0,0}};
        #pragma unroll
        for (int nt = 0; nt < 4; ++nt) {
            s16x8 b_0 = *(const s16x8*)&s_wall[4096 + ((nt * 2 + 0) * 64 + lane) * 8];
            s16x8 b_1 = *(const s16x8*)&s_wall[4096 + ((nt * 2 + 1) * 64 + lane) * 8];
            qacc[nt] = __builtin_amdgcn_mfma_f32_16x16x32_bf16(at0, b_0, qacc[nt], 0, 0, 0);
            qacc[nt] = __builtin_amdgcn_mfma_f32_16x16x32_bf16(at1, b_1, qacc[nt], 0, 0, 0);
        }
        #pragma unroll
        for (int nt = 0; nt < 4; ++nt)         // D[0][col] lives in lane=col (quad 0), reg 0
            qcv[nt] = __shfl(qacc[nt][0], r16) + ab1[nt * 16 + r16];
    }
    s16x8 w2r[4];
    #pragma unroll
    for (int fr = 0; fr < 4; ++fr)
        w2r[fr] = *(const s16x8*)&s_wall[8192 + (fr * 64 + lane) * 8];
    const float bias2_lo = ab2[r16], bias2_hi = ab2[16 + r16];
    const float w3_lo    = aw3[r16], w3_hi    = aw3[16 + r16];
    const float b3       = ab3[0];
    short* h1w = s_h1[wave];

    // ---- attention MLP per chunk (wave-independent); raw scores -> per-wave LDS ----
    #pragma unroll
    for (int ci = 0; ci < 4; ++ci) {
        if (!act[ci]) continue;                // wave-uniform branch
        f32x4 acc[4] = {{0,0,0,0},{0,0,0,0},{0,0,0,0},{0,0,0,0}};
        #pragma unroll
        for (int nt = 0; nt < 4; ++nt) {
            s16x8 b_0 = *(const s16x8*)&s_wall[((nt * 2 + 0) * 64 + lane) * 8];
            s16x8 b_1 = *(const s16x8*)&s_wall[((nt * 2 + 1) * 64 + lane) * 8];
            acc[nt] = __builtin_amdgcn_mfma_f32_16x16x32_bf16(af[ci][0], b_0, acc[nt], 0, 0, 0);
            acc[nt] = __builtin_amdgcn_mfma_f32_16x16x32_bf16(af[ci][1], b_1, acc[nt], 0, 0, 0);
        }
        #pragma unroll
        for (int nt = 0; nt < 4; ++nt)
            #pragma unroll
            for (int rr = 0; rr < 4; ++rr) {   // D: row=quad*4+rr, col=nt*16+r16
                float v = fmaxf(acc[nt][rr] + qcv[nt], 0.f);
                h1w[(quad * 4 + rr) * H1_PITCH + nt * 16 + r16] = f2bf(v);
            }
        __builtin_amdgcn_wave_barrier();       // wave-local LDS RAW

        s16x8 h0  = *(const s16x8*)&h1w[r16 * H1_PITCH + quad * 8];
        s16x8 h1v = *(const s16x8*)&h1w[r16 * H1_PITCH + 32 + quad * 8];
        f32x4 c2[2] = {{0,0,0,0},{0,0,0,0}};
        #pragma unroll
        for (int nt = 0; nt < 2; ++nt) {
            c2[nt] = __builtin_amdgcn_mfma_f32_16x16x32_bf16(h0,  w2r[nt * 2],     c2[nt], 0, 0, 0);
            c2[nt] = __builtin_amdgcn_mfma_f32_16x16x32_bf16(h1v, w2r[nt * 2 + 1], c2[nt], 0, 0, 0);
        }
        #pragma unroll
        for (int rr = 0; rr < 4; ++rr) {
            float p = fmaxf(c2[0][rr] + bias2_lo, 0.f) * w3_lo
                    + fmaxf(c2[1][rr] + bias2_hi, 0.f) * w3_hi;
            p += __shfl_xor(p, 8);
            p += __shfl_xor(p, 4);
            p += __shfl_xor(p, 2);
            p += __shfl_xor(p, 1);
            if (r16 == 0) s_sc[wave][ci * 16 + quad * 4 + rr] = p + b3;
        }
        __builtin_amdgcn_wave_barrier();
    }

    // ---- per-wave online softmax: max + sum(exp) over this wave's rows ----
    const int ci_l = lane >> 4;
    const int c_l  = wave + ci_l * 4;
    const int grow = c_l * 16 + r16;
    const bool valid = (c_l < 13) && (grow < len);
    float sc = valid ? s_sc[wave][lane] : -1e30f;
    float m = sc;
    #pragma unroll
    for (int off = 32; off; off >>= 1) m = fmaxf(m, __shfl_xor(m, off));
    float e = valid ? __expf(sc - m) : 0.f;
    #pragma unroll
    for (int off = 32; off; off >>= 1) e += __shfl_xor(e, off);

    // ---- register-retained pooling with weights exp(s - m_w) ----
    float p[16];
    #pragma unroll
    for (int i = 0; i < 16; ++i) p[i] = 0.f;
    #pragma unroll
    for (int ci = 0; ci < 4; ++ci) {
        if (!act[ci]) continue;
        const int row = (wave + ci * 4) * 16 + r16;
        const float w = (row < len) ? __expf(s_sc[wave][ci * 16 + r16] - m) : 0.f;
        #pragma unroll
        for (int j = 0; j < 8; ++j) {
            p[j]     += w * bf2f(af[ci][0][j]);
            p[8 + j] += w * bf2f(af[ci][1][j]);
        }
    }
    #pragma unroll
    for (int i = 0; i < 16; ++i) {             // reduce over rows (r16 bits)
        p[i] += __shfl_xor(p[i], 1);
        p[i] += __shfl_xor(p[i], 2);
        p[i] += __shfl_xor(p[i], 4);
        p[i] += __shfl_xor(p[i], 8);
    }
    if (r16 == 0) {
        #pragma unroll
        for (int j = 0; j < 8; ++j) {
            s_pool[wave][quad * 8 + j]      = p[j];
            s_pool[wave][32 + quad * 8 + j] = p[8 + j];
        }
    }
    if (lane == 0) { s_m[wave] = m; s_e[wave] = e; }
    __syncthreads();   // the only post-entry block barrier

    // ---- combine 4 wave-partials (online-softmax merge) + ctx + tgt -> comb ----
    short* comb = ws + CB_SH + b * 160;
    if (t < 64) {
        float gm = fmaxf(fmaxf(s_m[0], s_m[1]), fmaxf(s_m[2], s_m[3]));
        float s0 = __expf(s_m[0] - gm), s1 = __expf(s_m[1] - gm);
        float s2 = __expf(s_m[2] - gm), s3 = __expf(s_m[3] - gm);
        float denom = s0 * s_e[0] + s1 * s_e[1] + s2 * s_e[2] + s3 * s_e[3];
        float pooled = s0 * s_pool[0][t] + s1 * s_pool[1][t]
                     + s2 * s_pool[2][t] + s3 * s_pool[3][t];
        comb[t] = f2bf(pooled / denom);
    } else if (t < 96) {
        const int j = t - 64;
        float a = cb[j];
        #pragma unroll
        for (int k = 0; k < 9; ++k) a += ctx_feat[b * 9 + k] * cw[k * 32 + j];
        comb[128 + j] = f2bf(fmaxf(a, 0.f));
    } else if (t < 160) {
        comb[64 + (t - 96)] = embbf[tgt * 64 + (t - 96)];
    }
}

// ============================ K3: batched final MLP via MFMA (16 b's/wave) =====
__global__ __launch_bounds__(64)
void din_mlp_kernel(const float* __restrict__ mb1,
                    const float* __restrict__ mb2,
                    const float* __restrict__ mw3, const float* __restrict__ mb3,
                    const short* __restrict__ ws,
                    float* __restrict__ out)
{
    const int lane = threadIdx.x & 63;
    const int quad = lane >> 4, r16 = lane & 15;
    __shared__ short s_h1[16 * 136];
    __shared__ short s_h2[16 * 72];

    const int b0 = blockIdx.x * 16;
    const short* comb = ws + CB_SH;
    const short* w1   = ws + MW1T_SH;
    const short* w2   = ws + MW2T_SH;

    // layer1: (16x160) @ (160x128), K=160 in 5 steps
    s16x8 a[5];
    #pragma unroll
    for (int ks = 0; ks < 5; ++ks)
        a[ks] = *(const s16x8*)(comb + (b0 + r16) * 160 + ks * 32 + quad * 8);
    f32x4 acc[8] = {{0,0,0,0},{0,0,0,0},{0,0,0,0},{0,0,0,0},{0,0,0,0},{0,0,0,0},{0,0,0,0},{0,0,0,0}};
    #pragma unroll
    for (int nt = 0; nt < 8; ++nt)
        #pragma unroll
        for (int ks = 0; ks < 5; ++ks) {
            s16x8 bf = *(const s16x8*)(w1 + ((nt * 5 + ks) * 64 + lane) * 8);
            acc[nt] = __builtin_amdgcn_mfma_f32_16x16x32_bf16(a[ks], bf, acc[nt], 0, 0, 0);
        }
    #pragma unroll
    for (int nt = 0; nt < 8; ++nt) {
        float bias = mb1[nt * 16 + r16];
        #pragma unroll
        for (int rr = 0; rr < 4; ++rr)
            s_h1[(quad * 4 + rr) * 136 + nt * 16 + r16] = f2bf(fmaxf(acc[nt][rr] + bias, 0.f));
    }
    __builtin_amdgcn_wave_barrier();

    // layer2: (16x128) @ (128x64), K=128 in 4 steps
    s16x8 a2[4];
    #pragma unroll
    for (int ks = 0; ks < 4; ++ks)
        a2[ks] = *(const s16x8*)&s_h1[r16 * 136 + ks * 32 + quad * 8];
    f32x4 acc2[4] = {{0,0,0,0},{0,0,0,0},{0,0,0,0},{0,0,0,0}};
    #pragma unroll
    for (int nt = 0; nt < 4; ++nt)
        #pragma unroll
        for (int ks = 0; ks < 4; ++ks) {
            s16x8 bf = *(const s16x8*)(w2 + ((nt * 4 + ks) * 64 + lane) * 8);
            acc2[nt] = __builtin_amdgcn_mfma_f32_16x16x32_bf16(a2[ks], bf, acc2[nt], 0, 0, 0);
        }
    #pragma unroll
    for (int nt = 0; nt < 4; ++nt) {
        float bias = mb2[nt * 16 + r16];
        #pragma unroll
        for (int rr = 0; rr < 4; ++rr)
            s_h2[(quad * 4 + rr) * 72 + nt * 16 + r16] = f2bf(fmaxf(acc2[nt][rr] + bias, 0.f));
    }
    __builtin_amdgcn_wave_barrier();

    // layer3: (16x64) @ (64x1) + sigmoid
    float p = 0.f;
    #pragma unroll
    for (int j = 0; j < 16; ++j)
        p += bf2f(s_h2[r16 * 72 + quad * 16 + j]) * mw3[quad * 16 + j];
    p += __shfl_xor(p, 16);
    p += __shfl_xor(p, 32);
    if (quad == 0) out[b0 + r16] = 1.f / (1.f + __expf(-(p + mb3[0])));
}

extern "C" void kernel_launch(void* const* d_in, const int* in_sizes, int n_in,
                              void* d_out, int out_size, void* d_ws, size_t ws_size,
                              hipStream_t stream)
{
    const int*   item_seq  = (const int*)  d_in[0];
    // d_in[1] click_sequence: unused by the reference
    const int*   seq_len   = (const int*)  d_in[2];
    const int*   tgt_item  = (const int*)  d_in[3];
    const float* ctx_feat  = (const float*)d_in[4];
    const float* emb       = (const float*)d_in[5];
    const float* aw1 = (const float*)d_in[6];
    const float* ab1 = (const float*)d_in[7];
    const float* aw2 = (const float*)d_in[8];
    const float* ab2 = (const float*)d_in[9];
    const float* aw3 = (const float*)d_in[10];
    const float* ab3 = (const float*)d_in[11];
    const float* cw  = (const float*)d_in[12];
    const float* cb  = (const float*)d_in[13];
    const float* mw1 = (const float*)d_in[14];
    const float* mb1 = (const float*)d_in[15];
    const float* mw2 = (const float*)d_in[16];
    const float* mb2 = (const float*)d_in[17];
    const float* mw3 = (const float*)d_in[18];
    const float* mb3 = (const float*)d_in[19];
    float* out = (float*)d_out;
    short* ws  = (short*)d_ws;

    hipLaunchKernelGGL(din_prep_kernel, dim3(6259), dim3(256), 0, stream,
                       emb, aw1, aw2, mw1, mw2, ws);
    hipLaunchKernelGGL(din_att_v2, dim3(8192), dim3(256), 0, stream,
                       item_seq, seq_len, tgt_item, ctx_feat,
                       ab1, ab2, aw3, ab3, cw, cb, ws);
    hipLaunchKernelGGL(din_mlp_kernel, dim3(512), dim3(64), 0, stream,
                       mb1, mb2, mw3, mb3, ws, out);
}

// Round 9
// 192.405 us; speedup vs baseline: 1.1079x; 1.0235x over previous
//
#include <hip/hip_runtime.h>
#include <cmath>

typedef __attribute__((ext_vector_type(8))) short s16x8;   // 8 bf16 = 4 VGPRs (MFMA A/B frag)
typedef __attribute__((ext_vector_type(4))) short s16x4;
typedef __attribute__((ext_vector_type(4))) float f32x4;   // MFMA C/D frag

__device__ __forceinline__ short f2bf(float f) {
    union { float f; unsigned u; } v; v.f = f;
    unsigned r = v.u + 0x7FFFu + ((v.u >> 16) & 1u);   // RNE
    return (short)(r >> 16);
}
__device__ __forceinline__ float bf2f(short s) {
    union { unsigned u; float f; } v; v.u = ((unsigned)(unsigned short)s) << 16;
    return v.f;
}
__device__ __forceinline__ s16x8 cvt8(float4 a, float4 b) {
    s16x8 r = { f2bf(a.x), f2bf(a.y), f2bf(a.z), f2bf(a.w),
                f2bf(b.x), f2bf(b.y), f2bf(b.z), f2bf(b.w) };
    return r;
}

// ---- ws layout (no embedding table any more — 4.8 MB total) ----
// shorts: [w1seqF 4096][w1topF 4096][w2F 2048][mw1F 20480][mw2F 8192] = 38,912
// floats from float-ofs 19,456: [qc 8192*64]
// shorts from 1,087,488: [comb_bf16 8192*160]
#define W1SEQ_SH  0
#define W1TOP_SH  4096
#define W2_SH     8192
#define MW1T_SH   10240
#define MW2T_SH   30720
#define QC_F      19456
#define CB_SH     1087488

// ============================ K1: weight prep (8 blocks) ============================
__global__ __launch_bounds__(256)
void din_wprep_kernel(const float* __restrict__ aw1,
                      const float* __restrict__ aw2,
                      const float* __restrict__ mw1,
                      const float* __restrict__ mw2,
                      short* __restrict__ ws)
{
    const int wb = blockIdx.x;   // 0..7
    const int t = threadIdx.x;
    if (wb == 0) {               // w1seq frag-linear: frag = nt*2+ks (nt<4,ks<2)
        for (int idx = t; idx < 4096; idx += 256) {
            int j = idx & 7, lane = (idx >> 3) & 63, fr = idx >> 9;
            int n = (fr >> 1) * 16 + (lane & 15);
            int k = (fr & 1) * 32 + (lane >> 4) * 8 + j;
            ws[W1SEQ_SH + idx] = f2bf(aw1[(64 + k) * 64 + n]);
        }
    } else if (wb == 1) {        // w1top frag-linear
        for (int idx = t; idx < 4096; idx += 256) {
            int j = idx & 7, lane = (idx >> 3) & 63, fr = idx >> 9;
            int n = (fr >> 1) * 16 + (lane & 15);
            int k = (fr & 1) * 32 + (lane >> 4) * 8 + j;
            ws[W1TOP_SH + idx] = f2bf(aw1[k * 64 + n]);
        }
    } else if (wb == 2) {        // w2 frag-linear: frag = nt*2+ks (nt<2,ks<2)
        for (int idx = t; idx < 2048; idx += 256) {
            int j = idx & 7, lane = (idx >> 3) & 63, fr = idx >> 9;
            int n = (fr >> 1) * 16 + (lane & 15);
            int k = (fr & 1) * 32 + (lane >> 4) * 8 + j;
            ws[W2_SH + idx] = f2bf(aw2[k * 32 + n]);
        }
    } else if (wb == 3) {        // mw2 frag-linear: frag = nt*4+ks (nt<4,ks<4)
        for (int idx = t; idx < 8192; idx += 256) {
            int j = idx & 7, lane = (idx >> 3) & 63, fr = idx >> 9;
            int n = (fr >> 2) * 16 + (lane & 15);
            int k = (fr & 3) * 32 + (lane >> 4) * 8 + j;
            ws[MW2T_SH + idx] = f2bf(mw2[k * 64 + n]);
        }
    } else {                     // wb 4..7: mw1 frag-linear quarter: frag = nt*5+ks (nt<8,ks<5)
        const int base = (wb - 4) * 5120;
        for (int ii = t; ii < 5120; ii += 256) {
            int idx = base + ii;
            int j = idx & 7, lane = (idx >> 3) & 63, fr = idx >> 9;
            int nt = fr / 5, ks = fr - nt * 5;
            int n = nt * 16 + (lane & 15);
            int k = ks * 32 + (lane >> 4) * 8 + j;
            ws[MW1T_SH + idx] = f2bf(mw1[k * 128 + n]);
        }
    }
}

// ============================ K2: qc = tgt_emb @ aw1_top + ab1 ============================
__global__ __launch_bounds__(256)
void din_qc_kernel(const int* __restrict__ tgt_item,
                   const float* __restrict__ emb,
                   const float* __restrict__ ab1,
                   short* __restrict__ ws)
{
    const int t = threadIdx.x, lane = t & 63, wave = t >> 6;
    const int quad = lane >> 4, r16 = lane & 15;
    const short* w1t = ws + W1TOP_SH;
    float* qc = (float*)ws + QC_F;

    const int b0 = (blockIdx.x * 4 + wave) * 16;
    const int it = tgt_item[b0 + r16];
    const float* rp = emb + it * 64 + quad * 8;
    float4 v0 = *(const float4*)(rp),      v1 = *(const float4*)(rp + 4);
    float4 v2 = *(const float4*)(rp + 32), v3 = *(const float4*)(rp + 36);
    s16x8 a0 = cvt8(v0, v1);
    s16x8 a1 = cvt8(v2, v3);

    f32x4 acc[4] = {{0,0,0,0},{0,0,0,0},{0,0,0,0},{0,0,0,0}};
    #pragma unroll
    for (int nt = 0; nt < 4; ++nt) {
        s16x8 b_0 = *(const s16x8*)(w1t + ((nt * 2 + 0) * 64 + lane) * 8);
        s16x8 b_1 = *(const s16x8*)(w1t + ((nt * 2 + 1) * 64 + lane) * 8);
        acc[nt] = __builtin_amdgcn_mfma_f32_16x16x32_bf16(a0, b_0, acc[nt], 0, 0, 0);
        acc[nt] = __builtin_amdgcn_mfma_f32_16x16x32_bf16(a1, b_1, acc[nt], 0, 0, 0);
    }
    #pragma unroll
    for (int nt = 0; nt < 4; ++nt) {
        float bias = ab1[nt * 16 + r16];
        #pragma unroll
        for (int rr = 0; rr < 4; ++rr)   // D: row=quad*4+rr, col=nt*16+r16
            qc[(b0 + quad * 4 + rr) * 64 + nt * 16 + r16] = acc[nt][rr] + bias;
    }
}

// ============ K3: fused attention, fp32 direct gather, wave-independent softmax ============
#define H1_PITCH 72
__global__ __launch_bounds__(256)
void din_att_v3(const int* __restrict__ item_seq,
                const int* __restrict__ seq_len_p,
                const int* __restrict__ tgt_item,
                const float* __restrict__ ctx_feat,
                const float* __restrict__ emb,
                const float* __restrict__ ab2,
                const float* __restrict__ aw3, const float* __restrict__ ab3,
                const float* __restrict__ cw,  const float* __restrict__ cb,
                short* __restrict__ ws)
{
    const int t = threadIdx.x, lane = t & 63, wave = t >> 6;
    const int quad = lane >> 4, r16 = lane & 15;
    __shared__ short s_w1[4096];              // 8 KB frag-linear w1seq
    __shared__ short s_h1[4][16 * H1_PITCH];  // 9 KB per-wave H1 roundtrip
    __shared__ float s_sc[4][64];
    __shared__ float s_pool[4][64];
    __shared__ float s_m[4], s_e[4];

    const int b   = blockIdx.x;
    const int len = seq_len_p[b];
    const int tgt = tgt_item[b];

    // ---- stage w1seq frags (linear, conflict-free) ----
    {
        const s16x8* src = (const s16x8*)(ws + W1SEQ_SH);
        s16x8* dst = (s16x8*)s_w1;
        dst[t]       = src[t];
        dst[t + 256] = src[t + 256];
    }

    // ---- gathers: fp32 rows direct from emb, convert in-register, RETAIN ----
    bool act[4];
    s16x8 af[4][2];
    #pragma unroll
    for (int ci = 0; ci < 4; ++ci) {
        const int c = wave + ci * 4;
        act[ci] = (c < 13) && (c * 16 < len);
        if (act[ci]) {
            int r = c * 16 + r16; if (r > 199) r = 199;
            const int it = item_seq[b * 200 + r];
            const float* rp = emb + it * 64 + quad * 8;
            float4 v0 = *(const float4*)(rp),      v1 = *(const float4*)(rp + 4);
            float4 v2 = *(const float4*)(rp + 32), v3 = *(const float4*)(rp + 36);
            af[ci][0] = cvt8(v0, v1);
            af[ci][1] = cvt8(v2, v3);
        }
    }
    // ---- w2 frags from ws (frag-linear, coalesced), qc from ws ----
    s16x8 w2r[4];
    #pragma unroll
    for (int fr = 0; fr < 4; ++fr)
        w2r[fr] = *(const s16x8*)(ws + W2_SH + (fr * 64 + lane) * 8);
    const float* qcp = (const float*)ws + QC_F + b * 64;
    float qcv[4];
    #pragma unroll
    for (int nt = 0; nt < 4; ++nt) qcv[nt] = qcp[nt * 16 + r16];
    const float bias2_lo = ab2[r16], bias2_hi = ab2[16 + r16];
    const float w3_lo    = aw3[r16], w3_hi    = aw3[16 + r16];
    const float b3       = ab3[0];
    __syncthreads();   // weights staged

    short* h1w = s_h1[wave];

    // ---- attention MLP per chunk (wave-independent); raw scores -> per-wave LDS ----
    #pragma unroll
    for (int ci = 0; ci < 4; ++ci) {
        if (!act[ci]) continue;                // wave-uniform branch
        f32x4 acc[4] = {{0,0,0,0},{0,0,0,0},{0,0,0,0},{0,0,0,0}};
        #pragma unroll
        for (int nt = 0; nt < 4; ++nt) {
            s16x8 b_0 = *(const s16x8*)&s_w1[((nt * 2 + 0) * 64 + lane) * 8];
            s16x8 b_1 = *(const s16x8*)&s_w1[((nt * 2 + 1) * 64 + lane) * 8];
            acc[nt] = __builtin_amdgcn_mfma_f32_16x16x32_bf16(af[ci][0], b_0, acc[nt], 0, 0, 0);
            acc[nt] = __builtin_amdgcn_mfma_f32_16x16x32_bf16(af[ci][1], b_1, acc[nt], 0, 0, 0);
        }
        #pragma unroll
        for (int nt = 0; nt < 4; ++nt)
            #pragma unroll
            for (int rr = 0; rr < 4; ++rr) {   // D: row=quad*4+rr, col=nt*16+r16
                float v = fmaxf(acc[nt][rr] + qcv[nt], 0.f);
                h1w[(quad * 4 + rr) * H1_PITCH + nt * 16 + r16] = f2bf(v);
            }
        __builtin_amdgcn_wave_barrier();       // wave-local LDS RAW

        s16x8 h0  = *(const s16x8*)&h1w[r16 * H1_PITCH + quad * 8];
        s16x8 h1v = *(const s16x8*)&h1w[r16 * H1_PITCH + 32 + quad * 8];
        f32x4 c2[2] = {{0,0,0,0},{0,0,0,0}};
        #pragma unroll
        for (int nt = 0; nt < 2; ++nt) {
            c2[nt] = __builtin_amdgcn_mfma_f32_16x16x32_bf16(h0,  w2r[nt * 2],     c2[nt], 0, 0, 0);
            c2[nt] = __builtin_amdgcn_mfma_f32_16x16x32_bf16(h1v, w2r[nt * 2 + 1], c2[nt], 0, 0, 0);
        }
        #pragma unroll
        for (int rr = 0; rr < 4; ++rr) {
            float p = fmaxf(c2[0][rr] + bias2_lo, 0.f) * w3_lo
                    + fmaxf(c2[1][rr] + bias2_hi, 0.f) * w3_hi;
            p += __shfl_xor(p, 8);
            p += __shfl_xor(p, 4);
            p += __shfl_xor(p, 2);
            p += __shfl_xor(p, 1);
            if (r16 == 0) s_sc[wave][ci * 16 + quad * 4 + rr] = p + b3;
        }
        __builtin_amdgcn_wave_barrier();
    }

    // ---- per-wave online softmax over this wave's rows ----
    const int ci_l = lane >> 4;
    const int c_l  = wave + ci_l * 4;
    const int grow = c_l * 16 + r16;
    const bool valid = (c_l < 13) && (grow < len);
    float sc = valid ? s_sc[wave][lane] : -1e30f;
    float m = sc;
    #pragma unroll
    for (int off = 32; off; off >>= 1) m = fmaxf(m, __shfl_xor(m, off));
    float e = valid ? __expf(sc - m) : 0.f;
    #pragma unroll
    for (int off = 32; off; off >>= 1) e += __shfl_xor(e, off);

    // ---- register-retained pooling with weights exp(s - m_w) ----
    float p[16];
    #pragma unroll
    for (int i = 0; i < 16; ++i) p[i] = 0.f;
    #pragma unroll
    for (int ci = 0; ci < 4; ++ci) {
        if (!act[ci]) continue;
        const int row = (wave + ci * 4) * 16 + r16;
        const float w = (row < len) ? __expf(s_sc[wave][ci * 16 + r16] - m) : 0.f;
        #pragma unroll
        for (int j = 0; j < 8; ++j) {
            p[j]     += w * bf2f(af[ci][0][j]);
            p[8 + j] += w * bf2f(af[ci][1][j]);
        }
    }
    #pragma unroll
    for (int i = 0; i < 16; ++i) {             // reduce over rows (r16 bits)
        p[i] += __shfl_xor(p[i], 1);
        p[i] += __shfl_xor(p[i], 2);
        p[i] += __shfl_xor(p[i], 4);
        p[i] += __shfl_xor(p[i], 8);
    }
    if (r16 == 0) {
        #pragma unroll
        for (int j = 0; j < 8; ++j) {
            s_pool[wave][quad * 8 + j]      = p[j];
            s_pool[wave][32 + quad * 8 + j] = p[8 + j];
        }
    }
    if (lane == 0) { s_m[wave] = m; s_e[wave] = e; }
    __syncthreads();   // the only post-entry block barrier

    // ---- combine 4 wave-partials (online-softmax merge) + ctx + tgt -> comb ----
    short* comb = ws + CB_SH + b * 160;
    if (t < 64) {
        float gm = fmaxf(fmaxf(s_m[0], s_m[1]), fmaxf(s_m[2], s_m[3]));
        float s0 = __expf(s_m[0] - gm), s1 = __expf(s_m[1] - gm);
        float s2 = __expf(s_m[2] - gm), s3 = __expf(s_m[3] - gm);
        float denom = s0 * s_e[0] + s1 * s_e[1] + s2 * s_e[2] + s3 * s_e[3];
        float pooled = s0 * s_pool[0][t] + s1 * s_pool[1][t]
                     + s2 * s_pool[2][t] + s3 * s_pool[3][t];
        comb[t] = f2bf(pooled / denom);
    } else if (t < 96) {
        const int j = t - 64;
        float a = cb[j];
        #pragma unroll
        for (int k = 0; k < 9; ++k) a += ctx_feat[b * 9 + k] * cw[k * 32 + j];
        comb[128 + j] = f2bf(fmaxf(a, 0.f));
    } else if (t < 160) {
        comb[64 + (t - 96)] = f2bf(emb[tgt * 64 + (t - 96)]);
    }
}

// ============================ K4: batched final MLP via MFMA (16 b's/wave) =====
__global__ __launch_bounds__(64)
void din_mlp_kernel(const float* __restrict__ mb1,
                    const float* __restrict__ mb2,
                    const float* __restrict__ mw3, const float* __restrict__ mb3,
                    const short* __restrict__ ws,
                    float* __restrict__ out)
{
    const int lane = threadIdx.x & 63;
    const int quad = lane >> 4, r16 = lane & 15;
    __shared__ short s_h1[16 * 136];
    __shared__ short s_h2[16 * 72];

    const int b0 = blockIdx.x * 16;
    const short* comb = ws + CB_SH;
    const short* w1   = ws + MW1T_SH;
    const short* w2   = ws + MW2T_SH;

    // layer1: (16x160) @ (160x128), K=160 in 5 steps
    s16x8 a[5];
    #pragma unroll
    for (int ks = 0; ks < 5; ++ks)
        a[ks] = *(const s16x8*)(comb + (b0 + r16) * 160 + ks * 32 + quad * 8);
    f32x4 acc[8] = {{0,0,0,0},{0,0,0,0},{0,0,0,0},{0,0,0,0},{0,0,0,0},{0,0,0,0},{0,0,0,0},{0,0,0,0}};
    #pragma unroll
    for (int nt = 0; nt < 8; ++nt)
        #pragma unroll
        for (int ks = 0; ks < 5; ++ks) {
            s16x8 bf = *(const s16x8*)(w1 + ((nt * 5 + ks) * 64 + lane) * 8);
            acc[nt] = __builtin_amdgcn_mfma_f32_16x16x32_bf16(a[ks], bf, acc[nt], 0, 0, 0);
        }
    #pragma unroll
    for (int nt = 0; nt < 8; ++nt) {
        float bias = mb1[nt * 16 + r16];
        #pragma unroll
        for (int rr = 0; rr < 4; ++rr)
            s_h1[(quad * 4 + rr) * 136 + nt * 16 + r16] = f2bf(fmaxf(acc[nt][rr] + bias, 0.f));
    }
    __builtin_amdgcn_wave_barrier();

    // layer2: (16x128) @ (128x64), K=128 in 4 steps
    s16x8 a2[4];
    #pragma unroll
    for (int ks = 0; ks < 4; ++ks)
        a2[ks] = *(const s16x8*)&s_h1[r16 * 136 + ks * 32 + quad * 8];
    f32x4 acc2[4] = {{0,0,0,0},{0,0,0,0},{0,0,0,0},{0,0,0,0}};
    #pragma unroll
    for (int nt = 0; nt < 4; ++nt)
        #pragma unroll
        for (int ks = 0; ks < 4; ++ks) {
            s16x8 bf = *(const s16x8*)(w2 + ((nt * 4 + ks) * 64 + lane) * 8);
            acc2[nt] = __builtin_amdgcn_mfma_f32_16x16x32_bf16(a2[ks], bf, acc2[nt], 0, 0, 0);
        }
    #pragma unroll
    for (int nt = 0; nt < 4; ++nt) {
        float bias = mb2[nt * 16 + r16];
        #pragma unroll
        for (int rr = 0; rr < 4; ++rr)
            s_h2[(quad * 4 + rr) * 72 + nt * 16 + r16] = f2bf(fmaxf(acc2[nt][rr] + bias, 0.f));
    }
    __builtin_amdgcn_wave_barrier();

    // layer3: (16x64) @ (64x1) + sigmoid
    float p = 0.f;
    #pragma unroll
    for (int j = 0; j < 16; ++j)
        p += bf2f(s_h2[r16 * 72 + quad * 16 + j]) * mw3[quad * 16 + j];
    p += __shfl_xor(p, 16);
    p += __shfl_xor(p, 32);
    if (quad == 0) out[b0 + r16] = 1.f / (1.f + __expf(-(p + mb3[0])));
}

extern "C" void kernel_launch(void* const* d_in, const int* in_sizes, int n_in,
                              void* d_out, int out_size, void* d_ws, size_t ws_size,
                              hipStream_t stream)
{
    const int*   item_seq  = (const int*)  d_in[0];
    // d_in[1] click_sequence: unused by the reference
    const int*   seq_len   = (const int*)  d_in[2];
    const int*   tgt_item  = (const int*)  d_in[3];
    const float* ctx_feat  = (const float*)d_in[4];
    const float* emb       = (const float*)d_in[5];
    const float* aw1 = (const float*)d_in[6];
    const float* ab1 = (const float*)d_in[7];
    const float* aw2 = (const float*)d_in[8];
    const float* ab2 = (const float*)d_in[9];
    const float* aw3 = (const float*)d_in[10];
    const float* ab3 = (const float*)d_in[11];
    const float* cw  = (const float*)d_in[12];
    const float* cb  = (const float*)d_in[13];
    const float* mw1 = (const float*)d_in[14];
    const float* mb1 = (const float*)d_in[15];
    const float* mw2 = (const float*)d_in[16];
    const float* mb2 = (const float*)d_in[17];
    const float* mw3 = (const float*)d_in[18];
    const float* mb3 = (const float*)d_in[19];
    float* out = (float*)d_out;
    short* ws  = (short*)d_ws;

    hipLaunchKernelGGL(din_wprep_kernel, dim3(8), dim3(256), 0, stream,
                       aw1, aw2, mw1, mw2, ws);
    hipLaunchKernelGGL(din_qc_kernel, dim3(128), dim3(256), 0, stream,
                       tgt_item, emb, ab1, ws);
    hipLaunchKernelGGL(din_att_v3, dim3(8192), dim3(256), 0, stream,
                       item_seq, seq_len, tgt_item, ctx_feat, emb,
                       ab2, aw3, ab3, cw, cb, ws);
    hipLaunchKernelGGL(din_mlp_kernel, dim3(512), dim3(64), 0, stream,
                       mb1, mb2, mw3, mb3, ws, out);
}